// Round 1
// baseline (373.369 us; speedup 1.0000x reference)
//
#include <hip/hip_runtime.h>
#include <math.h>

// DGPLoss on MI355X.
// seg_feat: [B=4, C=64, H=512, W=512] f32, dep_true: [4,1,512,512] f32.
// 5x5 non-overlapping patches (Hp=Wp=102, rows/cols 0..509 used).
// Per pixel: seg_sq = sum_c (seg_center_c - seg_c)^2, dep_diff = |dep_center - dep|
// loss = exp(-dep_diff/10 - seg_sq); mask excludes center pixel, requires
// dep_diff>EPS, sqrt(seg_sq)>EPS (== seg_sq>EPS^2), dep>EPS.
// Output: sum(masked loss) / max(count,1).

#define EPSF 1e-8f
#define PH 5
#define HPATCH 102
#define HH 512
#define WW 512
#define CC 64

// Block: one (batch, patch-row, col-half). 320 threads = 5 waves.
// row = tid>>6 (0..4 within patch), lane = tid&63 -> 4 consecutive cols.
// Col-half 0: cols 0..255 (patches 0..51); half 1: cols 256..511 (patches 51..101),
// cols 510/511 masked out.

__global__ __launch_bounds__(320) void dgp_main(const float* __restrict__ seg,
                                                const float* __restrict__ dep,
                                                float* __restrict__ ws) {
  const int bid   = blockIdx.x;
  const int chunk = bid & 1;
  const int hp    = (bid >> 1) % HPATCH;
  const int b     = (bid >> 1) / HPATCH;
  const int h0    = hp * PH;
  const int hc    = h0 + 2;

  const int wp0 = chunk ? 51 : 0;   // first patch index covered by this half
  const int nwp = chunk ? 51 : 52;  // number of patches covered

  __shared__ float s_cent[52 * 65];  // [wpl][c], stride 65 -> bank = (wpl+c)%32
  __shared__ float s_depc[52];
  __shared__ float s_red[10];

  const int tid = threadIdx.x;
  const long seg_b = (long)b * CC * HH * WW;

  // ---- stage per-patch centers into LDS (consecutive lanes -> consecutive wpl) ----
  const int ntot = nwp * CC + nwp;
  for (int i = tid; i < ntot; i += 320) {
    if (i < nwp * CC) {
      int wpl = i % nwp;
      int c   = i / nwp;
      int wcol = (wp0 + wpl) * PH + 2;
      s_cent[wpl * 65 + c] = seg[seg_b + ((long)c * HH + hc) * WW + wcol];
    } else {
      int wpl  = i - nwp * CC;
      int wcol = (wp0 + wpl) * PH + 2;
      s_depc[wpl] = dep[((long)b * HH + hc) * WW + wcol];
    }
  }
  __syncthreads();

  const int row  = tid >> 6;
  const int lane = tid & 63;
  const int col0 = chunk * 256 + lane * 4;

  // per-col patch-local index (clamped; cols >=510 masked later)
  int w0 = min((col0 + 0) / PH - wp0, nwp - 1);
  int w1 = min((col0 + 1) / PH - wp0, nwp - 1);
  int w2 = min((col0 + 2) / PH - wp0, nwp - 1);
  int w3 = min((col0 + 3) / PH - wp0, nwp - 1);

  const float* cb0 = s_cent + w0 * 65;
  const float* cb1 = s_cent + w1 * 65;
  const float* cb2 = s_cent + w2 * 65;
  const float* cb3 = s_cent + w3 * 65;

  float acc0 = 0.f, acc1 = 0.f, acc2 = 0.f, acc3 = 0.f;
  const float* p = seg + seg_b + (long)(h0 + row) * WW + col0;

#pragma unroll 4
  for (int c = 0; c < CC; ++c) {
    float4 v = *(const float4*)(p + (long)c * (HH * WW));
    float c0 = cb0[c], c1 = cb1[c], c2 = cb2[c], c3 = cb3[c];
    float d0 = c0 - v.x;
    float d1 = c1 - v.y;
    float d2 = c2 - v.z;
    float d3 = c3 - v.w;
    acc0 = fmaf(d0, d0, acc0);
    acc1 = fmaf(d1, d1, acc1);
    acc2 = fmaf(d2, d2, acc2);
    acc3 = fmaf(d3, d3, acc3);
  }

  // ---- depth branch + mask + loss for this thread's 4 pixels ----
  float4 dv = *(const float4*)(dep + ((long)b * HH + h0 + row) * WW + col0);
  float dvals[4] = {dv.x, dv.y, dv.z, dv.w};
  float accs[4]  = {acc0, acc1, acc2, acc3};
  int wls[4]     = {w0, w1, w2, w3};

  float lsum = 0.f, lcnt = 0.f;
#pragma unroll
  for (int j = 0; j < 4; ++j) {
    int col = col0 + j;
    if (col < 510) {
      float dval = dvals[j];
      float dd   = fabsf(s_depc[wls[j]] - dval);
      float ssq  = accs[j];
      bool is_center = (row == 2) && (col % 5 == 2);
      bool m = (dd > EPSF) && (ssq > EPSF * EPSF) && (dval > EPSF) && !is_center;
      if (m) {
        lsum += expf(-(dd * 0.1f + ssq));
        lcnt += 1.f;
      }
    }
  }

  // ---- reduce: wave64 shuffle, then across the 5 waves via LDS ----
#pragma unroll
  for (int off = 32; off > 0; off >>= 1) {
    lsum += __shfl_down(lsum, off, 64);
    lcnt += __shfl_down(lcnt, off, 64);
  }
  if (lane == 0) {
    s_red[row]     = lsum;
    s_red[5 + row] = lcnt;
  }
  __syncthreads();
  if (tid == 0) {
    float a = 0.f, n = 0.f;
#pragma unroll
    for (int w = 0; w < 5; ++w) {
      a += s_red[w];
      n += s_red[5 + w];
    }
    atomicAdd(&ws[0], a);
    atomicAdd(&ws[1], n);
  }
}

__global__ void dgp_final(const float* __restrict__ ws, float* __restrict__ out) {
  out[0] = ws[0] / fmaxf(ws[1], 1.0f);
}

extern "C" void kernel_launch(void* const* d_in, const int* in_sizes, int n_in,
                              void* d_out, int out_size, void* d_ws, size_t ws_size,
                              hipStream_t stream) {
  const float* seg = (const float*)d_in[0];
  const float* dep = (const float*)d_in[1];
  float* out = (float*)d_out;
  float* ws  = (float*)d_ws;

  hipMemsetAsync(d_ws, 0, 2 * sizeof(float), stream);

  const int nblocks = 4 * HPATCH * 2;  // 816
  dgp_main<<<dim3(nblocks), dim3(320), 0, stream>>>(seg, dep, ws);
  dgp_final<<<1, 1, 0, stream>>>(ws, out);
}

// Round 2
// 365.505 us; speedup vs baseline: 1.0215x; 1.0215x over previous
//
#include <hip/hip_runtime.h>
#include <math.h>

// DGPLoss on MI355X.
// seg_feat: [B=4, C=64, H=512, W=512] f32, dep_true: [4,1,512,512] f32.
// 5x5 non-overlapping patches (102x102 patches, rows/cols 0..509 used).
// Per pixel: seg_sq = sum_c (seg_center_c - seg_c)^2, dep_diff = |dep_center - dep|
// loss = exp(-dep_diff/10 - seg_sq); mask excludes patch-center pixel, requires
// dep_diff>EPS, seg_sq>EPS^2, dep>EPS.  Output: sum(masked loss)/max(count,1).
//
// R2 structure: one block per (batch, patch-row, col-quarter) = 4*102*4 = 1632
// blocks (6.4 blocks/CU -> ~10% imbalance vs 25% at 816), 320 threads = 5 waves
// (wave = patch row), lane covers 2 consecutive cols via float2 loads.

#define EPSF 1e-8f
#define PH 5
#define HPATCH 102
#define HH 512
#define WW 512
#define CC 64
#define HW (HH * WW)

__global__ __launch_bounds__(320) void dgp_main(const float* __restrict__ seg,
                                                const float* __restrict__ dep,
                                                float* __restrict__ ws) {
  const int bid = blockIdx.x;
  const int q   = bid & 3;                  // col quarter (128 cols)
  const int hp  = (bid >> 2) % HPATCH;      // patch row
  const int b   = (bid >> 2) / HPATCH;      // batch
  const int h0  = hp * PH;
  const int hc  = h0 + 2;
  const int qbase = q * 128;

  // patches overlapping this quarter
  const int wp0   = qbase / PH;
  const int wpend = min((qbase + 127) / PH, HPATCH - 1);
  const int nwp   = wpend - wp0 + 1;        // 26 or 27

  __shared__ float s_cent[27 * 65];         // [wpl][c], stride 65 -> bank=(wpl+c)%32
  __shared__ float s_depc[27];
  __shared__ float s_red[10];

  const int tid = threadIdx.x;
  const long seg_b = (long)b * CC * HW;

  // ---- stage per-patch channel centers into LDS (div-free: 10 groups of 32) ----
  {
    const int grp = tid >> 5;               // 0..9 -> channel
    const int wpl = tid & 31;               // 0..31 -> patch-local
    if (wpl < nwp) {
      const long base = seg_b + (long)hc * WW + (wp0 + wpl) * PH + 2;
      for (int c = grp; c < CC; c += 10) {
        s_cent[wpl * 65 + c] = seg[base + (long)c * HW];
      }
    }
    if (tid < nwp) {
      s_depc[tid] = dep[((long)b * HH + hc) * WW + (wp0 + tid) * PH + 2];
    }
  }
  __syncthreads();

  const int row  = tid >> 6;                // 0..4 within patch
  const int lane = tid & 63;
  const int col0 = qbase + lane * 2;        // this thread's 2 cols

  int w0 = min(col0 / PH - wp0, nwp - 1);         // clamped; col>=510 masked later
  int w1 = min((col0 + 1) / PH - wp0, nwp - 1);

  const float* cb0 = s_cent + w0 * 65;
  const float* cb1 = s_cent + w1 * 65;

  float acc0 = 0.f, acc1 = 0.f;
  const float* p = seg + seg_b + (long)(h0 + row) * WW + col0;

#pragma unroll 8
  for (int c = 0; c < CC; ++c) {
    float2 v = *(const float2*)(p + (long)c * HW);
    float d0 = cb0[c] - v.x;
    float d1 = cb1[c] - v.y;
    acc0 = fmaf(d0, d0, acc0);
    acc1 = fmaf(d1, d1, acc1);
  }

  // ---- depth branch + mask + loss for this thread's 2 pixels ----
  float2 dv = *(const float2*)(dep + ((long)b * HH + h0 + row) * WW + col0);
  float dvals[2] = {dv.x, dv.y};
  float accs[2]  = {acc0, acc1};
  int wls[2]     = {w0, w1};

  float lsum = 0.f, lcnt = 0.f;
#pragma unroll
  for (int j = 0; j < 2; ++j) {
    int col = col0 + j;
    if (col < 510) {
      float dval = dvals[j];
      float dd   = fabsf(s_depc[wls[j]] - dval);
      float ssq  = accs[j];
      bool is_center = (row == 2) && (col % PH == 2);
      bool m = (dd > EPSF) && (ssq > EPSF * EPSF) && (dval > EPSF) && !is_center;
      if (m) {
        lsum += __expf(-(dd * 0.1f + ssq));
        lcnt += 1.f;
      }
    }
  }

  // ---- reduce: wave64 shuffle, then across the 5 waves via LDS ----
#pragma unroll
  for (int off = 32; off > 0; off >>= 1) {
    lsum += __shfl_down(lsum, off, 64);
    lcnt += __shfl_down(lcnt, off, 64);
  }
  if (lane == 0) {
    s_red[row]     = lsum;
    s_red[5 + row] = lcnt;
  }
  __syncthreads();
  if (tid == 0) {
    float a = 0.f, n = 0.f;
#pragma unroll
    for (int w = 0; w < 5; ++w) {
      a += s_red[w];
      n += s_red[5 + w];
    }
    atomicAdd(&ws[0], a);
    atomicAdd(&ws[1], n);
  }
}

__global__ void dgp_final(const float* __restrict__ ws, float* __restrict__ out) {
  out[0] = ws[0] / fmaxf(ws[1], 1.0f);
}

extern "C" void kernel_launch(void* const* d_in, const int* in_sizes, int n_in,
                              void* d_out, int out_size, void* d_ws, size_t ws_size,
                              hipStream_t stream) {
  const float* seg = (const float*)d_in[0];
  const float* dep = (const float*)d_in[1];
  float* out = (float*)d_out;
  float* ws  = (float*)d_ws;

  hipMemsetAsync(d_ws, 0, 2 * sizeof(float), stream);

  const int nblocks = 4 * HPATCH * 4;  // 1632
  dgp_main<<<dim3(nblocks), dim3(320), 0, stream>>>(seg, dep, ws);
  dgp_final<<<1, 1, 0, stream>>>(ws, out);
}